// Round 2
// baseline (1796.078 us; speedup 1.0000x reference)
//
#include <hip/hip_runtime.h>
#include <hip/hip_bf16.h>

// Shapes (fixed by the problem)
#define NB  8
#define NC  256
#define NCK 64
#define SEQ 2048

__device__ __forceinline__ float blk_max(float v, float* sc, int tid) {
#pragma unroll
  for (int off = 32; off > 0; off >>= 1) v = fmaxf(v, __shfl_down(v, off, 64));
  __syncthreads();
  if ((tid & 63) == 0) sc[tid >> 6] = v;
  __syncthreads();
  return fmaxf(fmaxf(sc[0], sc[1]), fmaxf(sc[2], sc[3]));
}

__device__ __forceinline__ float blk_sum(float v, float* sc, int tid) {
#pragma unroll
  for (int off = 32; off > 0; off >>= 1) v += __shfl_down(v, off, 64);
  __syncthreads();
  if ((tid & 63) == 0) sc[tid >> 6] = v;
  __syncthreads();
  return sc[0] + sc[1] + sc[2] + sc[3];
}

// out[o, n-space] = sum_c W[o,c] * in[b,c,n] (+bias). 32 o's per block, thread = n.
// TRANS=1: store as [B, N, C] (for x_q). TRANS=0: store as [B, C, N].
template <int CIN, int TRANS>
__global__ __launch_bounds__(256) void proj_kernel(
    const float* __restrict__ W, const float* __restrict__ in,
    const float* __restrict__ bias, float* __restrict__ out) {
  __shared__ float Wl[32 * CIN];
  const int tid = threadIdx.x;
  const int b  = blockIdx.x >> 3;
  const int n  = ((blockIdx.x & 7) << 8) + tid;
  const int og = blockIdx.y << 5;

  for (int i = tid; i < 32 * CIN; i += 256)
    Wl[i] = W[(size_t)(og + i / CIN) * CIN + (i % CIN)];
  __syncthreads();

  float acc[32];
#pragma unroll
  for (int j = 0; j < 32; ++j) acc[j] = 0.f;

  for (int c = 0; c < CIN; ++c) {
    float v = in[((size_t)b * CIN + c) * SEQ + n];
#pragma unroll
    for (int j = 0; j < 32; ++j) acc[j] = fmaf(Wl[j * CIN + c], v, acc[j]);
  }
  if (bias != nullptr) {
#pragma unroll
    for (int j = 0; j < 32; ++j) acc[j] += bias[og + j];
  }

  if (TRANS) {
    size_t base = ((size_t)b * SEQ + n) * NC + og;
#pragma unroll
    for (int j4 = 0; j4 < 8; ++j4) {
      float4 t = make_float4(acc[4 * j4], acc[4 * j4 + 1], acc[4 * j4 + 2], acc[4 * j4 + 3]);
      *(float4*)(out + base + 4 * j4) = t;
    }
  } else {
#pragma unroll
    for (int j = 0; j < 32; ++j)
      out[((size_t)b * NC + og + j) * SEQ + n] = acc[j];
  }
}

// Per (b, 8 query rows): full 2048-wide energy row in registers -> rowmax/rowsum,
// and atomic accumulation of per-key-column softmax sums (colsum).
__global__ __launch_bounds__(256) void softmax_stats_kernel(
    const float* __restrict__ xq, const float* __restrict__ xk,
    float* __restrict__ rowmax, float* __restrict__ rowsum, float* __restrict__ colsum) {
  __shared__ float xql[8 * NC];
  __shared__ float sc[4];
  const int tid = threadIdx.x;
  const int b  = blockIdx.x >> 8;
  const int r0 = (blockIdx.x & 255) << 3;

  for (int i = tid; i < 8 * NC; i += 256)
    xql[i] = xq[((size_t)b * SEQ + r0 + (i >> 8)) * NC + (i & 255)];
  __syncthreads();

  float e[64];
#pragma unroll
  for (int i = 0; i < 64; ++i) e[i] = 0.f;

  for (int c = 0; c < NC; ++c) {
    float kv[8];
#pragma unroll
    for (int j = 0; j < 8; ++j)
      kv[j] = xk[((size_t)b * NC + c) * SEQ + tid + (j << 8)];
#pragma unroll
    for (int r = 0; r < 8; ++r) {
      float qv = xql[(r << 8) + c];
#pragma unroll
      for (int j = 0; j < 8; ++j) e[(r << 3) + j] = fmaf(qv, kv[j], e[(r << 3) + j]);
    }
  }

  float rinv[8];
#pragma unroll
  for (int r = 0; r < 8; ++r) {
    float lm = -3.4e38f;
#pragma unroll
    for (int j = 0; j < 8; ++j) lm = fmaxf(lm, e[(r << 3) + j]);
    float rm = blk_max(lm, sc, tid);
    float ls = 0.f;
#pragma unroll
    for (int j = 0; j < 8; ++j) {
      float p = __expf(e[(r << 3) + j] - rm);
      e[(r << 3) + j] = p;
      ls += p;
    }
    float rs = blk_sum(ls, sc, tid);
    rinv[r] = 1.0f / rs;
    if (tid == 0) {
      rowmax[(size_t)b * SEQ + r0 + r] = rm;
      rowsum[(size_t)b * SEQ + r0 + r] = rs;
    }
  }
#pragma unroll
  for (int j = 0; j < 8; ++j) {
    float cs = 0.f;
#pragma unroll
    for (int r = 0; r < 8; ++r) cs += e[(r << 3) + j] * rinv[r];
    atomicAdd(&colsum[(size_t)b * SEQ + tid + (j << 8)], cs);
  }
}

// x_r[b, c, m] = (sum_n x_v[b,c,n] * P[b,n,m]) / (1e-9 + colsum[b,m]).
// Block = (b, 32 m-columns), thread = channel c. Energy recomputed tile-by-tile
// (each (n,m) energy computed exactly once across the whole grid).
__global__ __launch_bounds__(256) void xr_kernel(
    const float* __restrict__ xq, const float* __restrict__ xk, const float* __restrict__ xv,
    const float* __restrict__ rowmax, const float* __restrict__ rowsum,
    const float* __restrict__ colsum, float* __restrict__ xr) {
  __shared__ float xk_l[NC * 32];  // 32 KB
  __shared__ float xq_l[16 * NC];  // 16 KB
  __shared__ float p_l[16 * 32];
  __shared__ float cs_l[32];
  const int tid = threadIdx.x;
  const int b  = blockIdx.x >> 6;
  const int m0 = (blockIdx.x & 63) << 5;

  for (int i = tid; i < NC * 32; i += 256)
    xk_l[i] = xk[((size_t)b * NC + (i >> 5)) * SEQ + m0 + (i & 31)];
  if (tid < 32) cs_l[tid] = 1.0f / (1e-9f + colsum[(size_t)b * SEQ + m0 + tid]);

  float acc[32];
#pragma unroll
  for (int j = 0; j < 32; ++j) acc[j] = 0.f;

  for (int nt = 0; nt < SEQ / 16; ++nt) {
    const int n0 = nt << 4;
    __syncthreads();
    for (int i = tid; i < 16 * NC; i += 256)
      xq_l[i] = xq[((size_t)b * SEQ + n0 + (i >> 8)) * NC + (i & 255)];
    __syncthreads();
#pragma unroll
    for (int rep = 0; rep < 2; ++rep) {
      int idx = tid + (rep << 8);
      int nn = idx >> 5, mm = idx & 31;
      float ev = 0.f;
#pragma unroll 8
      for (int c2 = 0; c2 < NC; ++c2)
        ev = fmaf(xq_l[(nn << 8) + c2], xk_l[(c2 << 5) + mm], ev);
      float rm = rowmax[(size_t)b * SEQ + n0 + nn];
      float ri = 1.0f / rowsum[(size_t)b * SEQ + n0 + nn];
      p_l[idx] = __expf(ev - rm) * ri;
    }
    __syncthreads();
    const float* xvp = xv + ((size_t)b * NC + tid) * SEQ + n0;
    float xvr[16];
#pragma unroll
    for (int k4 = 0; k4 < 4; ++k4) {
      float4 t = *(const float4*)(xvp + 4 * k4);
      xvr[4 * k4 + 0] = t.x; xvr[4 * k4 + 1] = t.y;
      xvr[4 * k4 + 2] = t.z; xvr[4 * k4 + 3] = t.w;
    }
#pragma unroll
    for (int k = 0; k < 16; ++k) {
      float v = xvr[k];
#pragma unroll
      for (int m = 0; m < 32; ++m) acc[m] = fmaf(v, p_l[(k << 5) + m], acc[m]);
    }
  }

  size_t base = ((size_t)b * NC + tid) * SEQ + m0;
#pragma unroll
  for (int m4 = 0; m4 < 8; ++m4) {
    float4 t = make_float4(acc[4 * m4 + 0] * cs_l[4 * m4 + 0],
                           acc[4 * m4 + 1] * cs_l[4 * m4 + 1],
                           acc[4 * m4 + 2] * cs_l[4 * m4 + 2],
                           acc[4 * m4 + 3] * cs_l[4 * m4 + 3]);
    *(float4*)(xr + base + 4 * m4) = t;
  }
}

// BatchNorm training-mode stats: one block per channel, reduce over (B, N).
__global__ __launch_bounds__(256) void bnstats_kernel(
    const float* __restrict__ y, float* __restrict__ meanv, float* __restrict__ rstd) {
  __shared__ float sc[4];
  const int o = blockIdx.x, tid = threadIdx.x;
  float s = 0.f, sq = 0.f;
  for (int b = 0; b < NB; ++b) {
    const float* yp = y + ((size_t)b * NC + o) * SEQ;
    for (int n = tid; n < SEQ; n += 256) {
      float v = yp[n];
      s += v;
      sq = fmaf(v, v, sq);
    }
  }
  s  = blk_sum(s, sc, tid);
  sq = blk_sum(sq, sc, tid);
  if (tid == 0) {
    const float invn = 1.0f / (float)(NB * SEQ);
    float mean = s * invn;
    float var  = sq * invn - mean * mean;
    meanv[o] = mean;
    rstd[o]  = rsqrtf(var + 1e-5f);
  }
}

__global__ __launch_bounds__(256) void bnorm_kernel(
    const float* __restrict__ y, const float* __restrict__ meanv, const float* __restrict__ rstd,
    const float* __restrict__ gamma, const float* __restrict__ beta, float* __restrict__ out) {
  size_t e0 = ((size_t)blockIdx.x * 256 + threadIdx.x) * 4;
  int o = (int)((e0 >> 11) & (NC - 1));
  float a = gamma[o] * rstd[o];
  float c = beta[o] - meanv[o] * a;
  float4 v = *(const float4*)(y + e0);
  float4 r;
  r.x = fmaxf(0.f, fmaf(v.x, a, c));
  r.y = fmaxf(0.f, fmaf(v.y, a, c));
  r.z = fmaxf(0.f, fmaf(v.z, a, c));
  r.w = fmaxf(0.f, fmaf(v.w, a, c));
  *(float4*)(out + e0) = r;
}

extern "C" void kernel_launch(void* const* d_in, const int* in_sizes, int n_in,
                              void* d_out, int out_size, void* d_ws, size_t ws_size,
                              hipStream_t stream) {
  const float* q     = (const float*)d_in[0];
  const float* x     = (const float*)d_in[1];
  const float* Wq    = (const float*)d_in[2];
  const float* Wk    = (const float*)d_in[3];
  const float* Wv    = (const float*)d_in[4];
  const float* bv    = (const float*)d_in[5];
  const float* Wt    = (const float*)d_in[6];
  const float* bt    = (const float*)d_in[7];
  const float* gamma = (const float*)d_in[8];
  const float* beta  = (const float*)d_in[9];
  float* out = (float*)d_out;

  // Workspace layout (floats). Total = 5*4194304 + 3*16384 + 512 floats ~= 84.1 MB.
  float* ws = (float*)d_ws;
  const size_t SZ = (size_t)NB * NC * SEQ;  // 4,194,304
  float* xq = ws;            // [B, N, C]
  float* xk = xq + SZ;       // [B, C, N]
  float* xv = xk + SZ;       // [B, C, N]
  float* xr = xv + SZ;       // [B, C, N]
  float* y  = xr + SZ;       // [B, C, N]
  float* rowmax = y + SZ;    // [B, N]
  float* rowsum = rowmax + (size_t)NB * SEQ;
  float* colsum = rowsum + (size_t)NB * SEQ;
  float* meanv  = colsum + (size_t)NB * SEQ;  // [C]
  float* rstd   = meanv + NC;                 // [C]

  hipMemsetAsync(colsum, 0, (size_t)NB * SEQ * sizeof(float), stream);

  dim3 pg(64, 8);
  proj_kernel<NC, 1><<<pg, 256, 0, stream>>>(Wq, q, nullptr, xq);
  proj_kernel<NCK, 0><<<pg, 256, 0, stream>>>(Wk, x, nullptr, xk);
  proj_kernel<NC, 0><<<pg, 256, 0, stream>>>(Wv, q, bv, xv);
  softmax_stats_kernel<<<NB * SEQ / 8, 256, 0, stream>>>(xq, xk, rowmax, rowsum, colsum);
  xr_kernel<<<NB * (SEQ / 32), 256, 0, stream>>>(xq, xk, xv, rowmax, rowsum, colsum, xr);
  proj_kernel<NC, 0><<<pg, 256, 0, stream>>>(Wt, xr, bt, y);
  bnstats_kernel<<<NC, 256, 0, stream>>>(y, meanv, rstd);
  bnorm_kernel<<<(int)(SZ / 1024), 256, 0, stream>>>(y, meanv, rstd, gamma, beta, out);
}

// Round 3
// 536.147 us; speedup vs baseline: 3.3500x; 3.3500x over previous
//
#include <hip/hip_runtime.h>
#include <hip/hip_bf16.h>

// Shapes (fixed by the problem)
#define NB  8
#define NC  256
#define NCK 64
#define SEQ 2048

typedef short bfrag8 __attribute__((ext_vector_type(8)));   // 8 bf16 (4 VGPRs)
typedef float ffrag4 __attribute__((ext_vector_type(4)));   // 4 fp32 acc

#define MFMA16(a, b, c) __builtin_amdgcn_mfma_f32_16x16x32_bf16((a), (b), (c), 0, 0, 0)

static __device__ __forceinline__ unsigned short f2bf(float f) {
  return __builtin_bit_cast(unsigned short, (__bf16)f);  // RNE
}

__device__ __forceinline__ float blk_sum(float v, float* sc, int tid) {
#pragma unroll
  for (int off = 32; off > 0; off >>= 1) v += __shfl_down(v, off, 64);
  __syncthreads();
  if ((tid & 63) == 0) sc[tid >> 6] = v;
  __syncthreads();
  return sc[0] + sc[1] + sc[2] + sc[3];
}

// ---------- Projections to bf16 ----------
// out[o, n] = sum_c W[o,c] * in[b,c,n] (+bias). 32 o's per block, thread = n.
// TRANS=1: store bf16 [B, N, C] (K-contiguous for MFMA frags). TRANS=0: bf16 [B, C, N].
template <int CIN, int TRANS>
__global__ __launch_bounds__(256) void projb_kernel(
    const float* __restrict__ W, const float* __restrict__ in,
    const float* __restrict__ bias, unsigned short* __restrict__ out) {
  __shared__ float Wl[32 * CIN];
  const int tid = threadIdx.x;
  const int b  = blockIdx.x >> 3;
  const int n  = ((blockIdx.x & 7) << 8) + tid;
  const int og = blockIdx.y << 5;

  for (int i = tid; i < 32 * CIN; i += 256)
    Wl[i] = W[(size_t)(og + i / CIN) * CIN + (i % CIN)];
  __syncthreads();

  float acc[32];
#pragma unroll
  for (int j = 0; j < 32; ++j) acc[j] = 0.f;

  for (int c = 0; c < CIN; ++c) {
    float v = in[((size_t)b * CIN + c) * SEQ + n];
#pragma unroll
    for (int j = 0; j < 32; ++j) acc[j] = fmaf(Wl[j * CIN + c], v, acc[j]);
  }
  if (bias != nullptr) {
#pragma unroll
    for (int j = 0; j < 32; ++j) acc[j] += bias[og + j];
  }

  if (TRANS) {
    size_t base = ((size_t)b * SEQ + n) * NC + og;
    unsigned int pr[16];
#pragma unroll
    for (int j2 = 0; j2 < 16; ++j2)
      pr[j2] = (unsigned int)f2bf(acc[2 * j2]) | ((unsigned int)f2bf(acc[2 * j2 + 1]) << 16);
#pragma unroll
    for (int j8 = 0; j8 < 4; ++j8)
      *(uint4*)&out[base + 8 * j8] =
          make_uint4(pr[4 * j8], pr[4 * j8 + 1], pr[4 * j8 + 2], pr[4 * j8 + 3]);
  } else {
#pragma unroll
    for (int j = 0; j < 32; ++j)
      out[((size_t)b * NC + og + j) * SEQ + n] = f2bf(acc[j]);
  }
}

// ---------- Pass 1: rowinv[b,n] = 1 / sum_m exp(e[n,m]) via MFMA ----------
// Block: 512 thr = 8 waves, 32 query rows; wave w handles key strip [w*256, w*256+256).
__global__ __launch_bounds__(512) void rowsum_kernel(
    const unsigned short* __restrict__ xqT, const unsigned short* __restrict__ xkT,
    float* __restrict__ rowinv) {
  __shared__ float rs_l[32];
  const int tid = threadIdx.x;
  const int wv = tid >> 6, lane = tid & 63, quad = lane >> 4, ln = lane & 15;
  const int b  = blockIdx.x >> 6;
  const int n0 = (blockIdx.x & 63) << 5;

  if (tid < 32) rs_l[tid] = 0.f;
  __syncthreads();

  // A-frags: 2 row-sets x 16 q-rows, K=256 (8 frags each)
  bfrag8 aq[2][8];
#pragma unroll
  for (int rs = 0; rs < 2; ++rs) {
    const unsigned short* qp =
        xqT + ((size_t)b * SEQ + n0 + rs * 16 + ln) * NC + quad * 8;
#pragma unroll
    for (int kk = 0; kk < 8; ++kk) aq[rs][kk] = *(const bfrag8*)(qp + kk * 32);
  }

  float r0[4] = {0.f, 0.f, 0.f, 0.f}, r1[4] = {0.f, 0.f, 0.f, 0.f};
  for (int mt = 0; mt < 16; ++mt) {
    const int m = (wv << 8) + (mt << 4);
    bfrag8 bk[8];
    const unsigned short* kp = xkT + ((size_t)b * SEQ + m + ln) * NC + quad * 8;
#pragma unroll
    for (int kk = 0; kk < 8; ++kk) bk[kk] = *(const bfrag8*)(kp + kk * 32);
    ffrag4 e0 = {0.f, 0.f, 0.f, 0.f}, e1 = {0.f, 0.f, 0.f, 0.f};
#pragma unroll
    for (int kk = 0; kk < 8; ++kk) {
      e0 = MFMA16(aq[0][kk], bk[kk], e0);
      e1 = MFMA16(aq[1][kk], bk[kk], e1);
    }
#pragma unroll
    for (int r = 0; r < 4; ++r) {
      r0[r] += __expf(e0[r]);
      r1[r] += __expf(e1[r]);
    }
  }
  // reduce across ln (16 lanes within each quad hold different key columns)
#pragma unroll
  for (int msk = 1; msk < 16; msk <<= 1) {
#pragma unroll
    for (int r = 0; r < 4; ++r) {
      r0[r] += __shfl_xor(r0[r], msk, 64);
      r1[r] += __shfl_xor(r1[r], msk, 64);
    }
  }
  if (ln == 0) {
#pragma unroll
    for (int r = 0; r < 4; ++r) {
      atomicAdd(&rs_l[quad * 4 + r], r0[r]);
      atomicAdd(&rs_l[16 + quad * 4 + r], r1[r]);
    }
  }
  __syncthreads();
  if (tid < 32) rowinv[(size_t)b * SEQ + n0 + tid] = 1.0f / rs_l[tid];
}

// ---------- Pass 2: xr[b,c,m] = (sum_n xv[c,n] P[n,m]) / (1e-9 + colsum[m]) ----------
// Block: (b, 64-key tile), 512 thr = 8 waves. Loop n in 32-tiles:
//   E-phase: wave(nsub=wv&1, msub=wv>>1) computes E 16x16 via MFMA (persistent key
//   B-frags), P=exp(E)*rowinv -> bf16 -> LDS (B-operand layout, padded stride 40).
//   PV-phase: wave owns 32 channels x 4 key-subtiles, MFMA accumulate.
__global__ __launch_bounds__(512) void attn_kernel(
    const unsigned short* __restrict__ xqT, const unsigned short* __restrict__ xkT,
    const unsigned short* __restrict__ xv, const float* __restrict__ rowinv,
    float* __restrict__ xr) {
  __shared__ unsigned short xq_l[32 * 264];  // 32 q-rows x 256 C, stride 264 (bank-safe)
  __shared__ unsigned short p_l[64 * 40];    // 64 m-rows x 32 n, stride 40 (bank-safe)
  __shared__ float ri_l[32];
  __shared__ float cs_l[64];
  const int tid = threadIdx.x;
  const int wv = tid >> 6, lane = tid & 63, quad = lane >> 4, ln = lane & 15;
  const int b  = blockIdx.x >> 5;
  const int m0 = (blockIdx.x & 31) << 6;
  const int nsub = wv & 1, msub = wv >> 1;

  if (tid < 64) cs_l[tid] = 0.f;

  // persistent energy B-frags: keys m0 + msub*16 + ln, K=256
  bfrag8 bk[8];
  {
    const unsigned short* kp =
        xkT + ((size_t)b * SEQ + m0 + msub * 16 + ln) * NC + quad * 8;
#pragma unroll
    for (int kk = 0; kk < 8; ++kk) bk[kk] = *(const bfrag8*)(kp + kk * 32);
  }

  ffrag4 acc[2][4];  // [c-tile][m-subtile]
#pragma unroll
  for (int ct = 0; ct < 2; ++ct)
#pragma unroll
    for (int s = 0; s < 4; ++s) acc[ct][s] = (ffrag4){0.f, 0.f, 0.f, 0.f};
  float cs = 0.f;

  for (int nt = 0; nt < 64; ++nt) {
    const int n0 = nt << 5;
    // stage xq tile (32 x 256 bf16) + rowinv
    for (int i = tid; i < 32 * 32; i += 512) {
      int r = i >> 5, cc = (i & 31) << 3;
      *(uint4*)&xq_l[r * 264 + cc] =
          *(const uint4*)&xqT[((size_t)b * SEQ + n0 + r) * NC + cc];
    }
    if (tid < 32) ri_l[tid] = rowinv[(size_t)b * SEQ + n0 + tid];
    __syncthreads();

    // E-phase
    {
      ffrag4 e = {0.f, 0.f, 0.f, 0.f};
#pragma unroll
      for (int kk = 0; kk < 8; ++kk) {
        bfrag8 a = *(const bfrag8*)&xq_l[(nsub * 16 + ln) * 264 + kk * 32 + quad * 8];
        e = MFMA16(a, bk[kk], e);
      }
      unsigned short pu[4];
#pragma unroll
      for (int r = 0; r < 4; ++r) {
        float p = __expf(e[r]) * ri_l[nsub * 16 + quad * 4 + r];
        cs += p;
        pu[r] = f2bf(p);
      }
      *(uint2*)&p_l[(msub * 16 + ln) * 40 + nsub * 16 + quad * 4] =
          make_uint2((unsigned int)pu[0] | ((unsigned int)pu[1] << 16),
                     (unsigned int)pu[2] | ((unsigned int)pu[3] << 16));
    }
    __syncthreads();

    // PV-phase: wave owns channels [wv*32, wv*32+32), all 4 m-subtiles
    bfrag8 pb[4];
#pragma unroll
    for (int s = 0; s < 4; ++s)
      pb[s] = *(const bfrag8*)&p_l[(s * 16 + ln) * 40 + quad * 8];
#pragma unroll
    for (int ct = 0; ct < 2; ++ct) {
      bfrag8 av = *(const bfrag8*)&xv[((size_t)b * NC + wv * 32 + ct * 16 + ln) * SEQ +
                                      n0 + quad * 8];
#pragma unroll
      for (int s = 0; s < 4; ++s) acc[ct][s] = MFMA16(av, pb[s], acc[ct][s]);
    }
  }

  // colsum: cs is per-lane for key m = m0 + msub*16 + ln (summed over this wave's rows)
  cs += __shfl_down(cs, 32, 64);
  cs += __shfl_down(cs, 16, 64);
  if (lane < 16) atomicAdd(&cs_l[msub * 16 + ln], cs);
  __syncthreads();

  float invc[4];
#pragma unroll
  for (int s = 0; s < 4; ++s) invc[s] = 1.0f / (1e-9f + cs_l[s * 16 + ln]);

#pragma unroll
  for (int ct = 0; ct < 2; ++ct)
#pragma unroll
    for (int s = 0; s < 4; ++s)
#pragma unroll
      for (int r = 0; r < 4; ++r)
        xr[((size_t)b * NC + wv * 32 + ct * 16 + quad * 4 + r) * SEQ + m0 + s * 16 + ln] =
            acc[ct][s][r] * invc[s];
}

// ---------- fp32 proj for trans_conv ----------
__global__ __launch_bounds__(256) void projt_kernel(
    const float* __restrict__ W, const float* __restrict__ in,
    const float* __restrict__ bias, float* __restrict__ out) {
  __shared__ float Wl[32 * NC];
  const int tid = threadIdx.x;
  const int b  = blockIdx.x >> 3;
  const int n  = ((blockIdx.x & 7) << 8) + tid;
  const int og = blockIdx.y << 5;

  for (int i = tid; i < 32 * NC; i += 256)
    Wl[i] = W[(size_t)(og + (i >> 8)) * NC + (i & 255)];
  __syncthreads();

  float acc[32];
#pragma unroll
  for (int j = 0; j < 32; ++j) acc[j] = 0.f;
  for (int c = 0; c < NC; ++c) {
    float v = in[((size_t)b * NC + c) * SEQ + n];
#pragma unroll
    for (int j = 0; j < 32; ++j) acc[j] = fmaf(Wl[j * NC + c], v, acc[j]);
  }
#pragma unroll
  for (int j = 0; j < 32; ++j)
    out[((size_t)b * NC + og + j) * SEQ + n] = acc[j] + bias[og + j];
}

// ---------- BatchNorm (training stats) + ReLU ----------
__global__ __launch_bounds__(256) void bnstats_kernel(
    const float* __restrict__ y, float* __restrict__ meanv, float* __restrict__ rstd) {
  __shared__ float sc[4];
  const int o = blockIdx.x, tid = threadIdx.x;
  float s = 0.f, sq = 0.f;
  for (int b = 0; b < NB; ++b) {
    const float* yp = y + ((size_t)b * NC + o) * SEQ;
    for (int n = tid; n < SEQ; n += 256) {
      float v = yp[n];
      s += v;
      sq = fmaf(v, v, sq);
    }
  }
  s  = blk_sum(s, sc, tid);
  sq = blk_sum(sq, sc, tid);
  if (tid == 0) {
    const float invn = 1.0f / (float)(NB * SEQ);
    float mean = s * invn;
    float var  = sq * invn - mean * mean;
    meanv[o] = mean;
    rstd[o]  = rsqrtf(var + 1e-5f);
  }
}

__global__ __launch_bounds__(256) void bnorm_kernel(
    const float* __restrict__ y, const float* __restrict__ meanv, const float* __restrict__ rstd,
    const float* __restrict__ gamma, const float* __restrict__ beta, float* __restrict__ out) {
  size_t e0 = ((size_t)blockIdx.x * 256 + threadIdx.x) * 4;
  int o = (int)((e0 >> 11) & (NC - 1));
  float a = gamma[o] * rstd[o];
  float c = beta[o] - meanv[o] * a;
  float4 v = *(const float4*)(y + e0);
  float4 r;
  r.x = fmaxf(0.f, fmaf(v.x, a, c));
  r.y = fmaxf(0.f, fmaf(v.y, a, c));
  r.z = fmaxf(0.f, fmaf(v.z, a, c));
  r.w = fmaxf(0.f, fmaf(v.w, a, c));
  *(float4*)(out + e0) = r;
}

extern "C" void kernel_launch(void* const* d_in, const int* in_sizes, int n_in,
                              void* d_out, int out_size, void* d_ws, size_t ws_size,
                              hipStream_t stream) {
  const float* q     = (const float*)d_in[0];
  const float* x     = (const float*)d_in[1];
  const float* Wq    = (const float*)d_in[2];
  const float* Wk    = (const float*)d_in[3];
  const float* Wv    = (const float*)d_in[4];
  const float* bv    = (const float*)d_in[5];
  const float* Wt    = (const float*)d_in[6];
  const float* bt    = (const float*)d_in[7];
  const float* gamma = (const float*)d_in[8];
  const float* beta  = (const float*)d_in[9];
  float* out = (float*)d_out;

  const size_t SZ = (size_t)NB * NC * SEQ;  // 4,194,304
  unsigned short* xqT = (unsigned short*)d_ws;  // bf16 [B, N, C]
  unsigned short* xkT = xqT + SZ;               // bf16 [B, N(keys), C]
  unsigned short* xv  = xkT + SZ;               // bf16 [B, C, N]
  float* xr     = (float*)(xv + SZ);            // fp32 [B, C, N]
  float* y      = xr + SZ;                      // fp32 [B, C, N]
  float* rowinv = y + SZ;                       // fp32 [B, N]
  float* meanv  = rowinv + (size_t)NB * SEQ;    // [C]
  float* rstd   = meanv + NC;                   // [C]

  dim3 pg(64, 8);
  projb_kernel<NC, 1><<<pg, 256, 0, stream>>>(Wq, q, nullptr, xqT);
  projb_kernel<NCK, 1><<<pg, 256, 0, stream>>>(Wk, x, nullptr, xkT);
  projb_kernel<NC, 0><<<pg, 256, 0, stream>>>(Wv, q, bv, xv);
  rowsum_kernel<<<NB * 64, 512, 0, stream>>>(xqT, xkT, rowinv);
  attn_kernel<<<NB * 32, 512, 0, stream>>>(xqT, xkT, xv, rowinv, xr);
  projt_kernel<<<pg, 256, 0, stream>>>(Wt, xr, bt, y);
  bnstats_kernel<<<NC, 256, 0, stream>>>(y, meanv, rstd);
  bnorm_kernel<<<(int)(SZ / 1024), 256, 0, stream>>>(y, meanv, rstd, gamma, beta, out);
}

// Round 4
// 308.547 us; speedup vs baseline: 5.8211x; 1.7376x over previous
//
#include <hip/hip_runtime.h>
#include <hip/hip_bf16.h>

#define NB  8
#define NC  256
#define NCK 64
#define SEQ 2048

typedef unsigned short u16;
typedef short bfrag8 __attribute__((ext_vector_type(8)));   // 8 bf16 (4 VGPRs)
typedef float ffrag4 __attribute__((ext_vector_type(4)));   // 4 fp32 acc

#define MFMA16(a, b, c) __builtin_amdgcn_mfma_f32_16x16x32_bf16((a), (b), (c), 0, 0, 0)

static __device__ __forceinline__ u16 f2bf(float f) {
  return __builtin_bit_cast(u16, (__bf16)f);  // RNE
}
static __device__ __forceinline__ float bf2f(u16 u) {
  unsigned v = (unsigned)u << 16;
  return __builtin_bit_cast(float, v);
}

__device__ __forceinline__ float blk_sum(float v, float* sc, int tid) {
#pragma unroll
  for (int off = 32; off > 0; off >>= 1) v += __shfl_down(v, off, 64);
  __syncthreads();
  if ((tid & 63) == 0) sc[tid >> 6] = v;
  __syncthreads();
  return sc[0] + sc[1] + sc[2] + sc[3];
}

// ---------- W fp32 -> bf16 hi/lo (packed: Wq_hi|Wq_lo|Wv_hi|Wv_lo|Wt_hi|Wt_lo|Wk_hi|Wk_lo) ----------
__global__ __launch_bounds__(256) void wconv_kernel(
    const float* __restrict__ Wq, const float* __restrict__ Wv,
    const float* __restrict__ Wt, const float* __restrict__ Wk, u16* __restrict__ dst) {
  int id = blockIdx.x * 256 + threadIdx.x;
  if (id >= 212992) return;
  const float* src;
  int off, seg;
  if (id < 65536)       { src = Wq; off = 0;      seg = 65536; }
  else if (id < 131072) { src = Wv; off = 131072; seg = 65536; id -= 65536; }
  else if (id < 196608) { src = Wt; off = 262144; seg = 65536; id -= 131072; }
  else                  { src = Wk; off = 393216; seg = 16384; id -= 196608; }
  float v = src[id];
  u16 h = f2bf(v);
  u16 l = f2bf(v - bf2f(h));
  dst[off + id] = h;
  dst[off + seg + id] = l;
}

// ---------- transpose-convert: in fp32 [b][CIN][n] -> Thi/Tlo bf16 [b][n][CIN] ----------
template <int CIN>
__global__ __launch_bounds__(256) void tconv_kernel(
    const float* __restrict__ in, u16* __restrict__ Thi, u16* __restrict__ Tlo) {
  __shared__ float t[32][33];
  const int tid = threadIdx.x;
  const int b = blockIdx.x & 7, cg = blockIdx.x >> 3;
  const int c0 = cg << 5, n0 = blockIdx.y << 5;
  {
    int c = tid >> 3, m4 = (tid & 7) << 2;
    float4 v = *(const float4*)&in[((size_t)b * CIN + c0 + c) * SEQ + n0 + m4];
    t[c][m4 + 0] = v.x; t[c][m4 + 1] = v.y; t[c][m4 + 2] = v.z; t[c][m4 + 3] = v.w;
  }
  __syncthreads();
  {
    int n = tid >> 3, c4 = (tid & 7) << 2;
    u16 h[4], l[4];
#pragma unroll
    for (int j = 0; j < 4; ++j) {
      float v = t[c4 + j][n];
      h[j] = f2bf(v);
      l[j] = f2bf(v - bf2f(h[j]));
    }
    size_t base = ((size_t)b * SEQ + n0 + n) * CIN + c0 + c4;
    *(uint2*)&Thi[base] = make_uint2((unsigned)h[0] | ((unsigned)h[1] << 16),
                                     (unsigned)h[2] | ((unsigned)h[3] << 16));
    *(uint2*)&Tlo[base] = make_uint2((unsigned)l[0] | ((unsigned)l[1] << 16),
                                     (unsigned)l[2] | ((unsigned)l[3] << 16));
  }
}

// ---------- MFMA GEMM, hi/lo split (3-pass). act: [b][n][K] hi/lo; W: [256][K] hi/lo.
// WA=0 (act is A): out bf16 [b][n][256]. WA=1 (W is A): out [b][o][n], bf16 or fp32 (+bias).
template <int K, bool WA, bool OUTF32>
__global__ __launch_bounds__(256) void gemm_kernel(
    const u16* __restrict__ Ahi, const u16* __restrict__ Alo,
    const u16* __restrict__ Whi, const u16* __restrict__ Wlo,
    const float* __restrict__ bias, void* __restrict__ outp) {
  constexpr int SP = K + 8;
  extern __shared__ u16 lds[];  // 64*SP*2 shorts (hi rows then lo rows)
  const int tid = threadIdx.x;
  const int wv = tid >> 6, lane = tid & 63, quad = lane >> 4, ln = lane & 15;
  const int b = blockIdx.x & 7, nt = blockIdx.x >> 3;
  const int o0 = blockIdx.y << 6, n0 = nt << 6;

  constexpr int RW = K / 8;
  for (int i = tid; i < 64 * RW; i += 256) {
    int row = i / RW, kc = (i % RW) * 8;
    *(uint4*)&lds[row * SP + kc] = *(const uint4*)&Whi[(size_t)(o0 + row) * K + kc];
    *(uint4*)&lds[(64 + row) * SP + kc] = *(const uint4*)&Wlo[(size_t)(o0 + row) * K + kc];
  }
  constexpr int NA = K / 32;
  bfrag8 ahi[NA], alo[NA];
  {
    const u16* ap = Ahi + ((size_t)b * SEQ + n0 + wv * 16 + ln) * K + quad * 8;
    const u16* al = Alo + ((size_t)b * SEQ + n0 + wv * 16 + ln) * K + quad * 8;
#pragma unroll
    for (int a = 0; a < NA; ++a) {
      ahi[a] = *(const bfrag8*)(ap + a * 32);
      alo[a] = *(const bfrag8*)(al + a * 32);
    }
  }
  __syncthreads();

  ffrag4 acc[4];
#pragma unroll
  for (int ot = 0; ot < 4; ++ot) {
    ffrag4 e = {0.f, 0.f, 0.f, 0.f};
#pragma unroll
    for (int a = 0; a < NA; ++a) {
      bfrag8 wh = *(const bfrag8*)&lds[(ot * 16 + ln) * SP + a * 32 + quad * 8];
      bfrag8 wl = *(const bfrag8*)&lds[(64 + ot * 16 + ln) * SP + a * 32 + quad * 8];
      if (WA) {
        e = MFMA16(wh, ahi[a], e);
        e = MFMA16(wh, alo[a], e);
        e = MFMA16(wl, ahi[a], e);
      } else {
        e = MFMA16(ahi[a], wh, e);
        e = MFMA16(alo[a], wh, e);
        e = MFMA16(ahi[a], wl, e);
      }
    }
    acc[ot] = e;
  }
  __syncthreads();  // lds free for epilogue

  if (!WA) {
    u16* tl = lds;  // [64 n][72]
#pragma unroll
    for (int ot = 0; ot < 4; ++ot)
#pragma unroll
      for (int r = 0; r < 4; ++r)
        tl[(wv * 16 + quad * 4 + r) * 72 + ot * 16 + ln] = f2bf(acc[ot][r]);
    __syncthreads();
    u16* out = (u16*)outp;
    for (int i = tid; i < 64 * 8; i += 256) {
      int row = i >> 3, c8 = (i & 7) * 8;
      *(uint4*)&out[((size_t)b * SEQ + n0 + row) * NC + o0 + c8] = *(uint4*)&tl[row * 72 + c8];
    }
  } else {
    float* fl = (float*)lds;  // [64 o][68]
#pragma unroll
    for (int ot = 0; ot < 4; ++ot)
#pragma unroll
      for (int r = 0; r < 4; ++r)
        fl[(ot * 16 + quad * 4 + r) * 68 + wv * 16 + ln] = acc[ot][r];
    __syncthreads();
    for (int i = tid; i < 64 * 16; i += 256) {
      int row = i >> 4, n4 = (i & 15) * 4;
      float bb = (bias != nullptr) ? bias[o0 + row] : 0.f;
      const float* src = &fl[row * 68 + n4];
      if (OUTF32) {
        float4 v = *(const float4*)src;
        v.x += bb; v.y += bb; v.z += bb; v.w += bb;
        *(float4*)&((float*)outp)[((size_t)b * NC + o0 + row) * SEQ + n0 + n4] = v;
      } else {
        uint2 pk;
        pk.x = (unsigned)f2bf(src[0] + bb) | ((unsigned)f2bf(src[1] + bb) << 16);
        pk.y = (unsigned)f2bf(src[2] + bb) | ((unsigned)f2bf(src[3] + bb) << 16);
        *(uint2*)&((u16*)outp)[((size_t)b * NC + o0 + row) * SEQ + n0 + n4] = pk;
      }
    }
  }
}

// ---------- Pass 1: rowinv[b,n] = 1 / sum_m exp(e[n,m]) via MFMA (XCD-swizzled) ----------
__global__ __launch_bounds__(512) void rowsum_kernel(
    const u16* __restrict__ xqT, const u16* __restrict__ xkT, float* __restrict__ rowinv) {
  __shared__ float rs_l[32];
  const int tid = threadIdx.x;
  const int wv = tid >> 6, lane = tid & 63, quad = lane >> 4, ln = lane & 15;
  const int b = blockIdx.x & 7;
  const int n0 = (blockIdx.x >> 3) << 5;

  if (tid < 32) rs_l[tid] = 0.f;
  __syncthreads();

  bfrag8 aq[2][8];
#pragma unroll
  for (int rs = 0; rs < 2; ++rs) {
    const u16* qp = xqT + ((size_t)b * SEQ + n0 + rs * 16 + ln) * NC + quad * 8;
#pragma unroll
    for (int kk = 0; kk < 8; ++kk) aq[rs][kk] = *(const bfrag8*)(qp + kk * 32);
  }

  float r0[4] = {0.f, 0.f, 0.f, 0.f}, r1[4] = {0.f, 0.f, 0.f, 0.f};
  for (int mt = 0; mt < 16; ++mt) {
    const int m = (wv << 8) + (mt << 4);
    bfrag8 bk[8];
    const u16* kp = xkT + ((size_t)b * SEQ + m + ln) * NC + quad * 8;
#pragma unroll
    for (int kk = 0; kk < 8; ++kk) bk[kk] = *(const bfrag8*)(kp + kk * 32);
    ffrag4 e0 = {0.f, 0.f, 0.f, 0.f}, e1 = {0.f, 0.f, 0.f, 0.f};
#pragma unroll
    for (int kk = 0; kk < 8; ++kk) {
      e0 = MFMA16(aq[0][kk], bk[kk], e0);
      e1 = MFMA16(aq[1][kk], bk[kk], e1);
    }
#pragma unroll
    for (int r = 0; r < 4; ++r) {
      r0[r] += __expf(e0[r]);
      r1[r] += __expf(e1[r]);
    }
  }
#pragma unroll
  for (int msk = 1; msk < 16; msk <<= 1) {
#pragma unroll
    for (int r = 0; r < 4; ++r) {
      r0[r] += __shfl_xor(r0[r], msk, 64);
      r1[r] += __shfl_xor(r1[r], msk, 64);
    }
  }
  if (ln == 0) {
#pragma unroll
    for (int r = 0; r < 4; ++r) {
      atomicAdd(&rs_l[quad * 4 + r], r0[r]);
      atomicAdd(&rs_l[16 + quad * 4 + r], r1[r]);
    }
  }
  __syncthreads();
  if (tid < 32) rowinv[(size_t)b * SEQ + n0 + tid] = 1.0f / rs_l[tid];
}

// ---------- Pass 2 (n-split x2): U[half][b][c][m] = sum_{n in half} xv[c,n] P[n,m];
//            csum[half][b][m] = sum_{n in half} P[n,m] ----------
__global__ __launch_bounds__(512) void attn_kernel(
    const u16* __restrict__ xqT, const u16* __restrict__ xkT,
    const u16* __restrict__ xv, const float* __restrict__ rowinv,
    float* __restrict__ U, float* __restrict__ csum) {
  __shared__ u16 xq_l[32 * 264];
  __shared__ u16 p_l[64 * 36];  // stride 36 (18 dw): conflict-free-ish
  __shared__ float ri_l[32];
  __shared__ float cs_l[64];
  const int tid = threadIdx.x;
  const int wv = tid >> 6, lane = tid & 63, quad = lane >> 4, ln = lane & 15;
  const int b = blockIdx.x & 7;
  const int m0 = ((blockIdx.x >> 3) & 31) << 6;
  const int half = blockIdx.x >> 8;
  const int nsub = wv & 1, msub = wv >> 1;

  if (tid < 64) cs_l[tid] = 0.f;

  bfrag8 bk[8];
  {
    const u16* kp = xkT + ((size_t)b * SEQ + m0 + msub * 16 + ln) * NC + quad * 8;
#pragma unroll
    for (int kk = 0; kk < 8; ++kk) bk[kk] = *(const bfrag8*)(kp + kk * 32);
  }

  ffrag4 acc[2][4];
#pragma unroll
  for (int ct = 0; ct < 2; ++ct)
#pragma unroll
    for (int s = 0; s < 4; ++s) acc[ct][s] = (ffrag4){0.f, 0.f, 0.f, 0.f};
  float cs = 0.f;

  for (int nt = half * 32; nt < half * 32 + 32; ++nt) {
    const int n0 = nt << 5;
    __syncthreads();
    for (int i = tid; i < 32 * 32; i += 512) {
      int r = i >> 5, cc = (i & 31) << 3;
      *(uint4*)&xq_l[r * 264 + cc] = *(const uint4*)&xqT[((size_t)b * SEQ + n0 + r) * NC + cc];
    }
    if (tid < 32) ri_l[tid] = rowinv[(size_t)b * SEQ + n0 + tid];
    __syncthreads();

    {
      ffrag4 e = {0.f, 0.f, 0.f, 0.f};
#pragma unroll
      for (int kk = 0; kk < 8; ++kk) {
        bfrag8 a = *(const bfrag8*)&xq_l[(nsub * 16 + ln) * 264 + kk * 32 + quad * 8];
        e = MFMA16(a, bk[kk], e);
      }
      u16 pu[4];
#pragma unroll
      for (int r = 0; r < 4; ++r) {
        float p = __expf(e[r]) * ri_l[nsub * 16 + quad * 4 + r];
        cs += p;
        pu[r] = f2bf(p);
      }
      *(uint2*)&p_l[(msub * 16 + ln) * 36 + nsub * 16 + quad * 4] =
          make_uint2((unsigned)pu[0] | ((unsigned)pu[1] << 16),
                     (unsigned)pu[2] | ((unsigned)pu[3] << 16));
    }
    __syncthreads();

    union PB { uint2 u2[2]; bfrag8 f; };
    PB pb[4];
#pragma unroll
    for (int s = 0; s < 4; ++s) {
      pb[s].u2[0] = *(const uint2*)&p_l[(s * 16 + ln) * 36 + quad * 8];
      pb[s].u2[1] = *(const uint2*)&p_l[(s * 16 + ln) * 36 + quad * 8 + 4];
    }
#pragma unroll
    for (int ct = 0; ct < 2; ++ct) {
      bfrag8 av = *(const bfrag8*)&xv[((size_t)b * NC + wv * 32 + ct * 16 + ln) * SEQ + n0 + quad * 8];
#pragma unroll
      for (int s = 0; s < 4; ++s) acc[ct][s] = MFMA16(av, pb[s].f, acc[ct][s]);
    }
  }

  cs += __shfl_down(cs, 32, 64);
  cs += __shfl_down(cs, 16, 64);
  if (lane < 16) atomicAdd(&cs_l[msub * 16 + ln], cs);
  __syncthreads();
  if (tid < 64) csum[((size_t)half * NB + b) * SEQ + m0 + tid] = cs_l[tid];

  float* Uh = U + (size_t)half * NB * NC * SEQ;
#pragma unroll
  for (int ct = 0; ct < 2; ++ct)
#pragma unroll
    for (int s = 0; s < 4; ++s)
#pragma unroll
      for (int r = 0; r < 4; ++r)
        Uh[((size_t)b * NC + wv * 32 + ct * 16 + quad * 4 + r) * SEQ + m0 + s * 16 + ln] =
            acc[ct][s][r];
}

// ---------- combine: xrT_hi/lo [b][m][c] = bf16 split of (U0+U1)[c][m] / (1e-9 + colsum[m]) ----------
__global__ __launch_bounds__(256) void combine_kernel(
    const float* __restrict__ U, const float* __restrict__ csum,
    u16* __restrict__ xrT_hi, u16* __restrict__ xrT_lo) {
  __shared__ float t[32][33];
  __shared__ float im[32];
  const int tid = threadIdx.x;
  const int b = blockIdx.x & 7, cg = blockIdx.x >> 3;
  const int c0 = cg << 5, m0 = blockIdx.y << 5;
  const size_t SZi = (size_t)NB * NC * SEQ;

  if (tid < 32)
    im[tid] = 1.0f / (1e-9f + csum[(size_t)b * SEQ + m0 + tid] +
                      csum[((size_t)NB + b) * SEQ + m0 + tid]);
  __syncthreads();
  {
    int c = tid >> 3, m4 = (tid & 7) << 2;
    size_t idx = ((size_t)b * NC + c0 + c) * SEQ + m0 + m4;
    float4 u0 = *(const float4*)&U[idx];
    float4 u1 = *(const float4*)&U[SZi + idx];
    t[c][m4 + 0] = (u0.x + u1.x) * im[m4 + 0];
    t[c][m4 + 1] = (u0.y + u1.y) * im[m4 + 1];
    t[c][m4 + 2] = (u0.z + u1.z) * im[m4 + 2];
    t[c][m4 + 3] = (u0.w + u1.w) * im[m4 + 3];
  }
  __syncthreads();
  {
    int m = tid >> 3, c4 = (tid & 7) << 2;
    u16 h[4], l[4];
#pragma unroll
    for (int j = 0; j < 4; ++j) {
      float v = t[c4 + j][m];
      h[j] = f2bf(v);
      l[j] = f2bf(v - bf2f(h[j]));
    }
    size_t base = ((size_t)b * SEQ + m0 + m) * NC + c0 + c4;
    *(uint2*)&xrT_hi[base] = make_uint2((unsigned)h[0] | ((unsigned)h[1] << 16),
                                        (unsigned)h[2] | ((unsigned)h[3] << 16));
    *(uint2*)&xrT_lo[base] = make_uint2((unsigned)l[0] | ((unsigned)l[1] << 16),
                                        (unsigned)l[2] | ((unsigned)l[3] << 16));
  }
}

// ---------- BatchNorm partial stats (grid 2048 = b*ch) ----------
__global__ __launch_bounds__(256) void bnstats_kernel(
    const float* __restrict__ y, float* __restrict__ ssum, float* __restrict__ sqsum) {
  __shared__ float sc[4];
  const int tid = threadIdx.x;
  const int b = blockIdx.x >> 8, ch = blockIdx.x & 255;
  const float* yp = y + ((size_t)b * NC + ch) * SEQ;
  float s = 0.f, sq = 0.f;
#pragma unroll
  for (int hh = 0; hh < 2; ++hh) {
    float4 v = *(const float4*)&yp[hh * 1024 + 4 * tid];
    s += v.x + v.y + v.z + v.w;
    sq += v.x * v.x + v.y * v.y + v.z * v.z + v.w * v.w;
  }
  s = blk_sum(s, sc, tid);
  __syncthreads();
  sq = blk_sum(sq, sc, tid);
  if (tid == 0) {
    atomicAdd(&ssum[ch], s);
    atomicAdd(&sqsum[ch], sq);
  }
}

__global__ __launch_bounds__(256) void bnorm_kernel(
    const float* __restrict__ y, const float* __restrict__ ssum, const float* __restrict__ sqsum,
    const float* __restrict__ gamma, const float* __restrict__ beta, float* __restrict__ out) {
  size_t e0 = ((size_t)blockIdx.x * 256 + threadIdx.x) * 4;
  int o = (int)((e0 >> 11) & (NC - 1));
  const float invn = 1.0f / 16384.0f;
  float mean = ssum[o] * invn;
  float var = sqsum[o] * invn - mean * mean;
  float rs = rsqrtf(var + 1e-5f);
  float a = gamma[o] * rs;
  float c = beta[o] - mean * a;
  float4 v = *(const float4*)(y + e0);
  float4 r;
  r.x = fmaxf(0.f, fmaf(v.x, a, c));
  r.y = fmaxf(0.f, fmaf(v.y, a, c));
  r.z = fmaxf(0.f, fmaf(v.z, a, c));
  r.w = fmaxf(0.f, fmaf(v.w, a, c));
  *(float4*)(out + e0) = r;
}

extern "C" void kernel_launch(void* const* d_in, const int* in_sizes, int n_in,
                              void* d_out, int out_size, void* d_ws, size_t ws_size,
                              hipStream_t stream) {
  const float* q     = (const float*)d_in[0];
  const float* x     = (const float*)d_in[1];
  const float* Wq    = (const float*)d_in[2];
  const float* Wk    = (const float*)d_in[3];
  const float* Wv    = (const float*)d_in[4];
  const float* bv    = (const float*)d_in[5];
  const float* Wt    = (const float*)d_in[6];
  const float* bt    = (const float*)d_in[7];
  const float* gamma = (const float*)d_in[8];
  const float* beta  = (const float*)d_in[9];
  float* out = (float*)d_out;

  // Arena (phase-overlaid). SZ = 4,194,304 elems; SZB = 16 MB.
  const size_t SZ = (size_t)NB * NC * SEQ;
  const size_t SZB = SZ * 4;
  char* wsb = (char*)d_ws;
  u16* qT_hi = (u16*)(wsb);                 // [B][N][256] bf16
  u16* qT_lo = qT_hi + SZ;
  u16* xT_hi = (u16*)(wsb + SZB);           // [B][N][64] bf16
  u16* xT_lo = xT_hi + SZ / 4;
  float* U    = (float*)(wsb);              // [2][B][C][N] fp32 (overlays qT/xT after gemms)
  u16* xqT = (u16*)(wsb + 2 * SZB);         // [B][N][256] bf16
  u16* xkT = xqT + SZ;                      // [B][M][256] bf16
  u16* xrT_hi = xqT;                        // reuse after attn
  u16* xrT_lo = xkT;
  u16* xv = (u16*)(wsb + 3 * SZB);          // [B][C][N] bf16
  float* y = (float*)(wsb);                 // [B][C][N] fp32 (overlays U0 after combine)
  u16* wpack = (u16*)(wsb + 3 * SZB + SZB / 2);
  u16* Wq_hi = wpack, *Wq_lo = wpack + 65536;
  u16* Wv_hi = wpack + 131072, *Wv_lo = wpack + 196608;
  u16* Wt_hi = wpack + 262144, *Wt_lo = wpack + 327680;
  u16* Wk_hi = wpack + 393216, *Wk_lo = wpack + 409600;
  float* rowinv = (float*)(wpack + 425984);
  float* csum = rowinv + (size_t)NB * SEQ;        // [2][B][SEQ]
  float* ssum = csum + 2 * (size_t)NB * SEQ;      // [256]
  float* sqsum = ssum + NC;

  wconv_kernel<<<832, 256, 0, stream>>>(Wq, Wv, Wt, Wk, wpack);
  tconv_kernel<NC><<<dim3(64, 64), 256, 0, stream>>>(q, qT_hi, qT_lo);
  tconv_kernel<NCK><<<dim3(16, 64), 256, 0, stream>>>(x, xT_hi, xT_lo);

  const size_t shm256 = 64 * (256 + 8) * 2 * sizeof(u16);  // 67,584 B
  const size_t shm64  = 64 * (64 + 8) * 2 * sizeof(u16);   // 18,432 B
  gemm_kernel<256, false, false><<<dim3(256, 4), 256, shm256, stream>>>(
      qT_hi, qT_lo, Wq_hi, Wq_lo, nullptr, xqT);
  gemm_kernel<64, false, false><<<dim3(256, 4), 256, shm64, stream>>>(
      xT_hi, xT_lo, Wk_hi, Wk_lo, nullptr, xkT);
  gemm_kernel<256, true, false><<<dim3(256, 4), 256, shm256, stream>>>(
      qT_hi, qT_lo, Wv_hi, Wv_lo, bv, xv);

  rowsum_kernel<<<512, 512, 0, stream>>>(xqT, xkT, rowinv);
  attn_kernel<<<512, 512, 0, stream>>>(xqT, xkT, xv, rowinv, U, csum);
  combine_kernel<<<dim3(64, 64), 256, 0, stream>>>(U, csum, xrT_hi, xrT_lo);

  gemm_kernel<256, true, true><<<dim3(256, 4), 256, shm256, stream>>>(
      xrT_hi, xrT_lo, Wt_hi, Wt_lo, bt, y);

  hipMemsetAsync(ssum, 0, 2 * NC * sizeof(float), stream);
  bnstats_kernel<<<2048, 256, 0, stream>>>(y, ssum, sqsum);
  bnorm_kernel<<<4096, 256, 0, stream>>>(y, ssum, sqsum, gamma, beta, out);
}

// Round 5
// 292.278 us; speedup vs baseline: 6.1451x; 1.0557x over previous
//
#include <hip/hip_runtime.h>
#include <hip/hip_bf16.h>

#define NB  8
#define NC  256
#define NCK 64
#define SEQ 2048

typedef unsigned short u16;
typedef short bfrag8 __attribute__((ext_vector_type(8)));   // 8 bf16 (4 VGPRs)
typedef float ffrag4 __attribute__((ext_vector_type(4)));   // 4 fp32 acc

#define MFMA16(a, b, c) __builtin_amdgcn_mfma_f32_16x16x32_bf16((a), (b), (c), 0, 0, 0)

static __device__ __forceinline__ u16 f2bf(float f) {
  return __builtin_bit_cast(u16, (__bf16)f);  // RNE
}
static __device__ __forceinline__ float bf2f(u16 u) {
  unsigned v = (unsigned)u << 16;
  return __builtin_bit_cast(float, v);
}

__device__ __forceinline__ float blk_sum(float v, float* sc, int tid) {
#pragma unroll
  for (int off = 32; off > 0; off >>= 1) v += __shfl_down(v, off, 64);
  __syncthreads();
  if ((tid & 63) == 0) sc[tid >> 6] = v;
  __syncthreads();
  return sc[0] + sc[1] + sc[2] + sc[3];
}

// ---------- W fp32 -> bf16 hi/lo; last block zeroes ssum/sqsum ----------
__global__ __launch_bounds__(256) void wconv_kernel(
    const float* __restrict__ Wq, const float* __restrict__ Wv,
    const float* __restrict__ Wt, const float* __restrict__ Wk,
    u16* __restrict__ dst, float* __restrict__ zz) {
  int id = blockIdx.x * 256 + threadIdx.x;
  if (blockIdx.x == 832) {
    if (threadIdx.x < 256) { zz[threadIdx.x] = 0.f; zz[256 + threadIdx.x] = 0.f; }
    return;
  }
  const float* src;
  int off, seg;
  if (id < 65536)       { src = Wq; off = 0;      seg = 65536; }
  else if (id < 131072) { src = Wv; off = 131072; seg = 65536; id -= 65536; }
  else if (id < 196608) { src = Wt; off = 262144; seg = 65536; id -= 131072; }
  else                  { src = Wk; off = 393216; seg = 16384; id -= 196608; }
  float v = src[id];
  u16 h = f2bf(v);
  u16 l = f2bf(v - bf2f(h));
  dst[off + id] = h;
  dst[off + seg + id] = l;
}

// ---------- transpose-convert: in fp32 [b][CIN][n] -> Thi/Tlo bf16 [b][n][CIN] ----------
template <int CIN>
__global__ __launch_bounds__(256) void tconv_kernel(
    const float* __restrict__ in, u16* __restrict__ Thi, u16* __restrict__ Tlo) {
  __shared__ float t[32][33];
  const int tid = threadIdx.x;
  const int b = blockIdx.x & 7, cg = blockIdx.x >> 3;
  const int c0 = cg << 5, n0 = blockIdx.y << 5;
  {
    int c = tid >> 3, m4 = (tid & 7) << 2;
    float4 v = *(const float4*)&in[((size_t)b * CIN + c0 + c) * SEQ + n0 + m4];
    t[c][m4 + 0] = v.x; t[c][m4 + 1] = v.y; t[c][m4 + 2] = v.z; t[c][m4 + 3] = v.w;
  }
  __syncthreads();
  {
    int n = tid >> 3, c4 = (tid & 7) << 2;
    u16 h[4], l[4];
#pragma unroll
    for (int j = 0; j < 4; ++j) {
      float v = t[c4 + j][n];
      h[j] = f2bf(v);
      l[j] = f2bf(v - bf2f(h[j]));
    }
    size_t base = ((size_t)b * SEQ + n0 + n) * CIN + c0 + c4;
    *(uint2*)&Thi[base] = make_uint2((unsigned)h[0] | ((unsigned)h[1] << 16),
                                     (unsigned)h[2] | ((unsigned)h[3] << 16));
    *(uint2*)&Tlo[base] = make_uint2((unsigned)l[0] | ((unsigned)l[1] << 16),
                                     (unsigned)l[2] | ((unsigned)l[3] << 16));
  }
}

// ---------- MFMA GEMM, hi/lo split (3-pass). act: [b][n][K] hi/lo; W: [256][K] hi/lo.
// WA=0 (act is A): out bf16 [b][n][256]. WA=1 (W is A): out [b][o][n], bf16 or fp32 (+bias).
// OUTF32 path additionally accumulates BatchNorm partial sums into ssum/sqsum.
template <int K, bool WA, bool OUTF32>
__global__ __launch_bounds__(256) void gemm_kernel(
    const u16* __restrict__ Ahi, const u16* __restrict__ Alo,
    const u16* __restrict__ Whi, const u16* __restrict__ Wlo,
    const float* __restrict__ bias, void* __restrict__ outp,
    float* __restrict__ ssum, float* __restrict__ sqsum) {
  constexpr int SP = K + 8;
  extern __shared__ u16 lds[];  // 64*SP*2 shorts (hi rows then lo rows)
  static __shared__ float bsum[64], bsq[64];
  const int tid = threadIdx.x;
  const int wv = tid >> 6, lane = tid & 63, quad = lane >> 4, ln = lane & 15;
  const int b = blockIdx.x & 7, nt = blockIdx.x >> 3;
  const int o0 = blockIdx.y << 6, n0 = nt << 6;

  if (WA && OUTF32 && tid < 64) { bsum[tid] = 0.f; bsq[tid] = 0.f; }

  constexpr int RW = K / 8;
  for (int i = tid; i < 64 * RW; i += 256) {
    int row = i / RW, kc = (i % RW) * 8;
    *(uint4*)&lds[row * SP + kc] = *(const uint4*)&Whi[(size_t)(o0 + row) * K + kc];
    *(uint4*)&lds[(64 + row) * SP + kc] = *(const uint4*)&Wlo[(size_t)(o0 + row) * K + kc];
  }
  constexpr int NA = K / 32;
  bfrag8 ahi[NA], alo[NA];
  {
    const u16* ap = Ahi + ((size_t)b * SEQ + n0 + wv * 16 + ln) * K + quad * 8;
    const u16* al = Alo + ((size_t)b * SEQ + n0 + wv * 16 + ln) * K + quad * 8;
#pragma unroll
    for (int a = 0; a < NA; ++a) {
      ahi[a] = *(const bfrag8*)(ap + a * 32);
      alo[a] = *(const bfrag8*)(al + a * 32);
    }
  }
  __syncthreads();

  ffrag4 acc[4];
#pragma unroll
  for (int ot = 0; ot < 4; ++ot) {
    ffrag4 e = {0.f, 0.f, 0.f, 0.f};
#pragma unroll
    for (int a = 0; a < NA; ++a) {
      bfrag8 wh = *(const bfrag8*)&lds[(ot * 16 + ln) * SP + a * 32 + quad * 8];
      bfrag8 wl = *(const bfrag8*)&lds[(64 + ot * 16 + ln) * SP + a * 32 + quad * 8];
      if (WA) {
        e = MFMA16(wh, ahi[a], e);
        e = MFMA16(wh, alo[a], e);
        e = MFMA16(wl, ahi[a], e);
      } else {
        e = MFMA16(ahi[a], wh, e);
        e = MFMA16(alo[a], wh, e);
        e = MFMA16(ahi[a], wl, e);
      }
    }
    acc[ot] = e;
  }
  __syncthreads();  // lds free for epilogue

  if (!WA) {
    u16* tl = lds;  // [64 n][72]
#pragma unroll
    for (int ot = 0; ot < 4; ++ot)
#pragma unroll
      for (int r = 0; r < 4; ++r)
        tl[(wv * 16 + quad * 4 + r) * 72 + ot * 16 + ln] = f2bf(acc[ot][r]);
    __syncthreads();
    u16* out = (u16*)outp;
    for (int i = tid; i < 64 * 8; i += 256) {
      int row = i >> 3, c8 = (i & 7) * 8;
      *(uint4*)&out[((size_t)b * SEQ + n0 + row) * NC + o0 + c8] = *(uint4*)&tl[row * 72 + c8];
    }
  } else {
    float* fl = (float*)lds;  // [64 o][68]
#pragma unroll
    for (int ot = 0; ot < 4; ++ot)
#pragma unroll
      for (int r = 0; r < 4; ++r)
        fl[(ot * 16 + quad * 4 + r) * 68 + wv * 16 + ln] = acc[ot][r];
    __syncthreads();
    for (int i = tid; i < 64 * 16; i += 256) {
      int row = i >> 4, n4 = (i & 15) * 4;
      float bb = (bias != nullptr) ? bias[o0 + row] : 0.f;
      const float* src = &fl[row * 68 + n4];
      if (OUTF32) {
        float4 v = *(const float4*)src;
        v.x += bb; v.y += bb; v.z += bb; v.w += bb;
        *(float4*)&((float*)outp)[((size_t)b * NC + o0 + row) * SEQ + n0 + n4] = v;
        float s = v.x + v.y + v.z + v.w;
        float sq = v.x * v.x + v.y * v.y + v.z * v.z + v.w * v.w;
        atomicAdd(&bsum[row], s);
        atomicAdd(&bsq[row], sq);
      } else {
        uint2 pk;
        pk.x = (unsigned)f2bf(src[0] + bb) | ((unsigned)f2bf(src[1] + bb) << 16);
        pk.y = (unsigned)f2bf(src[2] + bb) | ((unsigned)f2bf(src[3] + bb) << 16);
        *(uint2*)&((u16*)outp)[((size_t)b * NC + o0 + row) * SEQ + n0 + n4] = pk;
      }
    }
    if (OUTF32) {
      __syncthreads();
      if (tid < 64) {
        atomicAdd(&ssum[o0 + tid], bsum[tid]);
        atomicAdd(&sqsum[o0 + tid], bsq[tid]);
      }
    }
  }
}

// ---------- Pass 1: rowinv[b,n] = 1 / sum_m exp(e[n,m]) via MFMA (XCD-swizzled) ----------
__global__ __launch_bounds__(512) void rowsum_kernel(
    const u16* __restrict__ xqT, const u16* __restrict__ xkT, float* __restrict__ rowinv) {
  __shared__ float rs_l[32];
  const int tid = threadIdx.x;
  const int wv = tid >> 6, lane = tid & 63, quad = lane >> 4, ln = lane & 15;
  const int b = blockIdx.x & 7;
  const int n0 = (blockIdx.x >> 3) << 5;

  if (tid < 32) rs_l[tid] = 0.f;
  __syncthreads();

  bfrag8 aq[2][8];
#pragma unroll
  for (int rs = 0; rs < 2; ++rs) {
    const u16* qp = xqT + ((size_t)b * SEQ + n0 + rs * 16 + ln) * NC + quad * 8;
#pragma unroll
    for (int kk = 0; kk < 8; ++kk) aq[rs][kk] = *(const bfrag8*)(qp + kk * 32);
  }

  float r0[4] = {0.f, 0.f, 0.f, 0.f}, r1[4] = {0.f, 0.f, 0.f, 0.f};
  for (int mt = 0; mt < 16; ++mt) {
    const int m = (wv << 8) + (mt << 4);
    bfrag8 bk[8];
    const u16* kp = xkT + ((size_t)b * SEQ + m + ln) * NC + quad * 8;
#pragma unroll
    for (int kk = 0; kk < 8; ++kk) bk[kk] = *(const bfrag8*)(kp + kk * 32);
    ffrag4 e0 = {0.f, 0.f, 0.f, 0.f}, e1 = {0.f, 0.f, 0.f, 0.f};
#pragma unroll
    for (int kk = 0; kk < 8; ++kk) {
      e0 = MFMA16(aq[0][kk], bk[kk], e0);
      e1 = MFMA16(aq[1][kk], bk[kk], e1);
    }
#pragma unroll
    for (int r = 0; r < 4; ++r) {
      r0[r] += __expf(e0[r]);
      r1[r] += __expf(e1[r]);
    }
  }
#pragma unroll
  for (int msk = 1; msk < 16; msk <<= 1) {
#pragma unroll
    for (int r = 0; r < 4; ++r) {
      r0[r] += __shfl_xor(r0[r], msk, 64);
      r1[r] += __shfl_xor(r1[r], msk, 64);
    }
  }
  if (ln == 0) {
#pragma unroll
    for (int r = 0; r < 4; ++r) {
      atomicAdd(&rs_l[quad * 4 + r], r0[r]);
      atomicAdd(&rs_l[16 + quad * 4 + r], r1[r]);
    }
  }
  __syncthreads();
  if (tid < 32) rowinv[(size_t)b * SEQ + n0 + tid] = 1.0f / rs_l[tid];
}

// ---------- Pass 2 (n-split x2, register-prefetched): U (bf16) + csum partials ----------
__global__ __launch_bounds__(512, 4) void attn_kernel(
    const u16* __restrict__ xqT, const u16* __restrict__ xkT,
    const u16* __restrict__ xv, const float* __restrict__ rowinv,
    u16* __restrict__ U, float* __restrict__ csum) {
  __shared__ u16 xq_l[32 * 264];
  __shared__ u16 p_l[64 * 36];
  __shared__ float ri_l[32];
  __shared__ float cs_l[64];
  const int tid = threadIdx.x;
  const int wv = tid >> 6, lane = tid & 63, quad = lane >> 4, ln = lane & 15;
  const int b = blockIdx.x & 7;
  const int m0 = ((blockIdx.x >> 3) & 31) << 6;
  const int half = blockIdx.x >> 8;
  const int nsub = wv & 1, msub = wv >> 1;
  const int nt0 = half * 32, ntEnd = nt0 + 32;

  if (tid < 64) cs_l[tid] = 0.f;

  // persistent energy B-frags: keys m0 + msub*16 + ln, K=256
  bfrag8 bk[8];
  {
    const u16* kp = xkT + ((size_t)b * SEQ + m0 + msub * 16 + ln) * NC + quad * 8;
#pragma unroll
    for (int kk = 0; kk < 8; ++kk) bk[kk] = *(const bfrag8*)(kp + kk * 32);
  }

  // prefetch state: xq tile (32B/thread), rowinv, and this wave's xv frags
  const int prow = tid >> 4, pcol = (tid & 15) << 4;
  uint4 pf0, pf1;
  float ripf = 0.f;
  bfrag8 avpf0, avpf1;
  {
    const int n0 = nt0 << 5;
    const u16* src = &xqT[((size_t)b * SEQ + n0 + prow) * NC + pcol];
    pf0 = *(const uint4*)src;
    pf1 = *(const uint4*)(src + 8);
    if (tid < 32) ripf = rowinv[(size_t)b * SEQ + n0 + tid];
    const u16* vp = &xv[((size_t)b * NC + wv * 32 + ln) * SEQ + n0 + quad * 8];
    avpf0 = *(const bfrag8*)vp;
    avpf1 = *(const bfrag8*)(vp + 16 * SEQ);
  }

  ffrag4 acc[2][4];
#pragma unroll
  for (int ct = 0; ct < 2; ++ct)
#pragma unroll
    for (int s = 0; s < 4; ++s) acc[ct][s] = (ffrag4){0.f, 0.f, 0.f, 0.f};
  float cs = 0.f;

  for (int nt = nt0; nt < ntEnd; ++nt) {
    // (a) commit prefetched data to LDS / regs
    bfrag8 av0 = avpf0, av1 = avpf1;
    *(uint4*)&xq_l[prow * 264 + pcol] = pf0;
    *(uint4*)&xq_l[prow * 264 + pcol + 8] = pf1;
    if (tid < 32) ri_l[tid] = ripf;
    // (b) issue next iteration's loads (latency hidden across the barriers)
    {
      const int ntn = (nt + 1 < ntEnd) ? nt + 1 : nt;
      const int n0n = ntn << 5;
      const u16* src = &xqT[((size_t)b * SEQ + n0n + prow) * NC + pcol];
      pf0 = *(const uint4*)src;
      pf1 = *(const uint4*)(src + 8);
      if (tid < 32) ripf = rowinv[(size_t)b * SEQ + n0n + tid];
      const u16* vp = &xv[((size_t)b * NC + wv * 32 + ln) * SEQ + n0n + quad * 8];
      avpf0 = *(const bfrag8*)vp;
      avpf1 = *(const bfrag8*)(vp + 16 * SEQ);
    }
    // (c)
    __syncthreads();
    // (d) E-phase: wave (nsub, msub) computes a 16x16 energy tile, writes P to LDS
    {
      ffrag4 e = {0.f, 0.f, 0.f, 0.f};
#pragma unroll
      for (int kk = 0; kk < 8; ++kk) {
        bfrag8 a = *(const bfrag8*)&xq_l[(nsub * 16 + ln) * 264 + kk * 32 + quad * 8];
        e = MFMA16(a, bk[kk], e);
      }
      u16 pu[4];
#pragma unroll
      for (int r = 0; r < 4; ++r) {
        float p = __expf(e[r]) * ri_l[nsub * 16 + quad * 4 + r];
        cs += p;
        pu[r] = f2bf(p);
      }
      *(uint2*)&p_l[(msub * 16 + ln) * 36 + nsub * 16 + quad * 4] =
          make_uint2((unsigned)pu[0] | ((unsigned)pu[1] << 16),
                     (unsigned)pu[2] | ((unsigned)pu[3] << 16));
    }
    // (e)
    __syncthreads();
    // (f) PV: wave owns channels [wv*32, wv*32+32), all 4 m-subtiles
    union PB { uint2 u2[2]; bfrag8 f; };
    PB pb[4];
#pragma unroll
    for (int s = 0; s < 4; ++s) {
      pb[s].u2[0] = *(const uint2*)&p_l[(s * 16 + ln) * 36 + quad * 8];
      pb[s].u2[1] = *(const uint2*)&p_l[(s * 16 + ln) * 36 + quad * 8 + 4];
    }
#pragma unroll
    for (int s = 0; s < 4; ++s) {
      acc[0][s] = MFMA16(av0, pb[s].f, acc[0][s]);
      acc[1][s] = MFMA16(av1, pb[s].f, acc[1][s]);
    }
  }

  cs += __shfl_down(cs, 32, 64);
  cs += __shfl_down(cs, 16, 64);
  if (lane < 16) atomicAdd(&cs_l[msub * 16 + ln], cs);
  __syncthreads();
  if (tid < 64) csum[((size_t)half * NB + b) * SEQ + m0 + tid] = cs_l[tid];

  u16* Uh = U + (size_t)half * NB * NC * SEQ;
#pragma unroll
  for (int ct = 0; ct < 2; ++ct)
#pragma unroll
    for (int s = 0; s < 4; ++s)
#pragma unroll
      for (int r = 0; r < 4; ++r)
        Uh[((size_t)b * NC + wv * 32 + ct * 16 + quad * 4 + r) * SEQ + m0 + s * 16 + ln] =
            f2bf(acc[ct][s][r]);
}

// ---------- combine: xrT_hi/lo [b][m][c] = bf16 split of (U0+U1)[c][m] / (1e-9 + colsum[m]) ----------
__global__ __launch_bounds__(256) void combine_kernel(
    const u16* __restrict__ U, const float* __restrict__ csum,
    u16* __restrict__ xrT_hi, u16* __restrict__ xrT_lo) {
  __shared__ float t[32][33];
  __shared__ float im[32];
  const int tid = threadIdx.x;
  const int b = blockIdx.x & 7, cg = blockIdx.x >> 3;
  const int c0 = cg << 5, m0 = blockIdx.y << 5;
  const size_t SZi = (size_t)NB * NC * SEQ;

  if (tid < 32)
    im[tid] = 1.0f / (1e-9f + csum[(size_t)b * SEQ + m0 + tid] +
                      csum[((size_t)NB + b) * SEQ + m0 + tid]);
  __syncthreads();
  {
    int c = tid >> 3, m4 = (tid & 7) << 2;
    size_t idx = ((size_t)b * NC + c0 + c) * SEQ + m0 + m4;
    uint2 a0 = *(const uint2*)&U[idx];
    uint2 a1 = *(const uint2*)&U[SZi + idx];
    const u16* p0 = (const u16*)&a0;
    const u16* p1 = (const u16*)&a1;
#pragma unroll
    for (int j = 0; j < 4; ++j)
      t[c][m4 + j] = (bf2f(p0[j]) + bf2f(p1[j])) * im[m4 + j];
  }
  __syncthreads();
  {
    int m = tid >> 3, c4 = (tid & 7) << 2;
    u16 h[4], l[4];
#pragma unroll
    for (int j = 0; j < 4; ++j) {
      float v = t[c4 + j][m];
      h[j] = f2bf(v);
      l[j] = f2bf(v - bf2f(h[j]));
    }
    size_t base = ((size_t)b * SEQ + m0 + m) * NC + c0 + c4;
    *(uint2*)&xrT_hi[base] = make_uint2((unsigned)h[0] | ((unsigned)h[1] << 16),
                                        (unsigned)h[2] | ((unsigned)h[3] << 16));
    *(uint2*)&xrT_lo[base] = make_uint2((unsigned)l[0] | ((unsigned)l[1] << 16),
                                        (unsigned)l[2] | ((unsigned)l[3] << 16));
  }
}

// ---------- BN normalize + ReLU ----------
__global__ __launch_bounds__(256) void bnorm_kernel(
    const float* __restrict__ y, const float* __restrict__ ssum, const float* __restrict__ sqsum,
    const float* __restrict__ gamma, const float* __restrict__ beta, float* __restrict__ out) {
  size_t e0 = ((size_t)blockIdx.x * 256 + threadIdx.x) * 4;
  int o = (int)((e0 >> 11) & (NC - 1));
  const float invn = 1.0f / 16384.0f;
  float mean = ssum[o] * invn;
  float var = sqsum[o] * invn - mean * mean;
  float rs = rsqrtf(var + 1e-5f);
  float a = gamma[o] * rs;
  float c = beta[o] - mean * a;
  float4 v = *(const float4*)(y + e0);
  float4 r;
  r.x = fmaxf(0.f, fmaf(v.x, a, c));
  r.y = fmaxf(0.f, fmaf(v.y, a, c));
  r.z = fmaxf(0.f, fmaf(v.z, a, c));
  r.w = fmaxf(0.f, fmaf(v.w, a, c));
  *(float4*)(out + e0) = r;
}

extern "C" void kernel_launch(void* const* d_in, const int* in_sizes, int n_in,
                              void* d_out, int out_size, void* d_ws, size_t ws_size,
                              hipStream_t stream) {
  const float* q     = (const float*)d_in[0];
  const float* x     = (const float*)d_in[1];
  const float* Wq    = (const float*)d_in[2];
  const float* Wk    = (const float*)d_in[3];
  const float* Wv    = (const float*)d_in[4];
  const float* bv    = (const float*)d_in[5];
  const float* Wt    = (const float*)d_in[6];
  const float* bt    = (const float*)d_in[7];
  const float* gamma = (const float*)d_in[8];
  const float* beta  = (const float*)d_in[9];
  float* out = (float*)d_out;

  // Arena (phase-overlaid). SZ = 4,194,304 elems; SZB = 16 MB.
  const size_t SZ = (size_t)NB * NC * SEQ;
  const size_t SZB = SZ * 4;
  char* wsb = (char*)d_ws;
  u16* qT_hi = (u16*)(wsb);                 // [B][N][256] bf16
  u16* qT_lo = qT_hi + SZ;
  u16* xT_hi = (u16*)(wsb + SZB);           // [B][N][64] bf16
  u16* xT_lo = xT_hi + SZ / 4;
  u16* U     = (u16*)(wsb);                 // [2][B][C][N] bf16 (overlays qT after gemms)
  u16* xqT = (u16*)(wsb + 2 * SZB);         // [B][N][256] bf16
  u16* xkT = xqT + SZ;                      // [B][M][256] bf16
  u16* xrT_hi = xqT;                        // reuse after attn
  u16* xrT_lo = xkT;
  u16* xv = (u16*)(wsb + 3 * SZB);          // [B][C][N] bf16
  float* y = (float*)(wsb);                 // [B][C][N] fp32 (overlays U after combine)
  u16* wpack = (u16*)(wsb + 3 * SZB + SZB / 2);
  u16* Wq_hi = wpack, *Wq_lo = wpack + 65536;
  u16* Wv_hi = wpack + 131072, *Wv_lo = wpack + 196608;
  u16* Wt_hi = wpack + 262144, *Wt_lo = wpack + 327680;
  u16* Wk_hi = wpack + 393216, *Wk_lo = wpack + 409600;
  float* rowinv = (float*)(wpack + 425984);
  float* csum = rowinv + (size_t)NB * SEQ;        // [2][B][SEQ]
  float* ssum = csum + 2 * (size_t)NB * SEQ;      // [256]
  float* sqsum = ssum + NC;                       // [256] (contiguous with ssum)

  wconv_kernel<<<833, 256, 0, stream>>>(Wq, Wv, Wt, Wk, wpack, ssum);
  tconv_kernel<NC><<<dim3(64, 64), 256, 0, stream>>>(q, qT_hi, qT_lo);
  tconv_kernel<NCK><<<dim3(16, 64), 256, 0, stream>>>(x, xT_hi, xT_lo);

  const size_t shm256 = 64 * (256 + 8) * 2 * sizeof(u16);  // 67,584 B
  const size_t shm64  = 64 * (64 + 8) * 2 * sizeof(u16);   // 18,432 B
  gemm_kernel<256, false, false><<<dim3(256, 4), 256, shm256, stream>>>(
      qT_hi, qT_lo, Wq_hi, Wq_lo, nullptr, xqT, nullptr, nullptr);
  gemm_kernel<64, false, false><<<dim3(256, 4), 256, shm64, stream>>>(
      xT_hi, xT_lo, Wk_hi, Wk_lo, nullptr, xkT, nullptr, nullptr);
  gemm_kernel<256, true, false><<<dim3(256, 4), 256, shm256, stream>>>(
      qT_hi, qT_lo, Wv_hi, Wv_lo, bv, xv, nullptr, nullptr);

  rowsum_kernel<<<512, 512, 0, stream>>>(xqT, xkT, rowinv);
  attn_kernel<<<512, 512, 0, stream>>>(xqT, xkT, xv, rowinv, U, csum);
  combine_kernel<<<dim3(64, 64), 256, 0, stream>>>(U, csum, xrT_hi, xrT_lo);

  gemm_kernel<256, true, true><<<dim3(256, 4), 256, shm256, stream>>>(
      xrT_hi, xrT_lo, Wt_hi, Wt_lo, bt, y, ssum, sqsum);

  bnorm_kernel<<<4096, 256, 0, stream>>>(y, ssum, sqsum, gamma, beta, out);
}